// Round 3
// baseline (2306.874 us; speedup 1.0000x reference)
//
#include <hip/hip_runtime.h>

#define B_   8
#define D_   256
#define T_   4096
#define NQ_  8
#define K_   1024

#define IDX_OFF  ((size_t)B_ * T_ * D_)             // 8388608
#define LOSS_OFF (IDX_OFF + (size_t)NQ_ * B_ * T_)  // 8650752

// ---- workspace layout (bytes) ----
#define XT_OFF   0ull                      // float xT[32768][256]  (32 MB)
#define CB16_OFF 33554432ull               // half cb16[8][32][16][64][8] frag layout (4 MB)
#define CN_OFF   37748736ull               // float cnorm[8192] (f64-accurate)
#define LB_OFF   37781504ull               // double lossbuf[8]

typedef _Float16 half8 __attribute__((ext_vector_type(8)));   // 4 VGPR MFMA A/B frag
typedef float   f32x16 __attribute__((ext_vector_type(16)));  // MFMA C/D

__device__ __forceinline__ ushort f2h(float f) {
  return __builtin_bit_cast(ushort, (_Float16)f);   // v_cvt_f16_f32, RNE
}

__device__ __forceinline__ void ldsdma16(const ushort* g, ushort* l) {
  // per-lane src (g already includes lane*16B); LDS dst wave-uniform base + lane*16
  __builtin_amdgcn_global_load_lds((const __attribute__((address_space(1))) uint*)g,
                                   (__attribute__((address_space(3))) uint*)l, 16, 0, 0);
}

// insert (sc, c10) into running sorted top-3 (v1<=v2<=v3, pk: [9:0]=i1 [19:10]=i2 [29:20]=i3)
__device__ __forceinline__ void ins3(float& v1, float& v2, float& v3, uint& pk, float sc, uint c10) {
  if (sc < v1)      { v3 = v2; v2 = v1; v1 = sc; pk = ((pk & 0xFFFFFu) << 10) | c10; }
  else if (sc < v2) { v3 = v2; v2 = sc; pk = (pk & 0x3FFu) | (c10 << 10) | (((pk >> 10) & 0x3FFu) << 20); }
  else if (sc < v3) { v3 = sc; pk = (pk & 0xFFFFFu) | (c10 << 20); }
}

// ---- prep 1: x [B,D,T] -> xT f32 [row=b*T+t][d] ----
__global__ void prep_xT(const float* __restrict__ x, float* __restrict__ xT) {
  __shared__ float tile[64][65];
  const int bidx = blockIdx.x;                 // 8 b * 4 dchunk * 64 tchunk
  const int b = bidx >> 8, dc = (bidx >> 6) & 3, tc = bidx & 63;
  const int d0 = dc * 64, t0 = tc * 64;
  const int tid = threadIdx.x;
  {
    const int tt = tid & 63, dg = tid >> 6;
    for (int i = 0; i < 16; ++i) {
      const int d = dg * 16 + i;
      tile[d][tt] = x[((size_t)(b * D_ + d0 + d)) * T_ + t0 + tt];
    }
  }
  __syncthreads();
  {
    const int dw = tid & 63, tg = tid >> 6;
    for (int i = 0; i < 16; ++i) {
      const int t = tg * 16 + i;
      xT[((size_t)b * T_ + t0 + t) * D_ + d0 + dw] = tile[dw][t];
    }
  }
}

// ---- prep 2: cb f32 -> fp16 in MFMA-B fragment/staging order + f64-accurate cnorm ----
// layout: cb16[stage][tile(code>>5)][ks(k>>4)][lane][8]; lane = ((k>>3)&1)*32 + (code&31), j=k&7
__global__ void prep_cb16(const float* __restrict__ cb, ushort* __restrict__ cb16,
                          float* __restrict__ cnorm) {
  const int tid = threadIdx.x, w = tid >> 6, l = tid & 63;
  const int code = blockIdx.x * 4 + w;         // grid 2048
  const int s = code >> 10, ci = code & 1023, tile = ci >> 5, n = ci & 31;
  const float* row = cb + (size_t)code * D_;
  const float4 v = *(const float4*)(row + l * 4);
  double nrm = (double)v.x * v.x + (double)v.y * v.y + (double)v.z * v.z + (double)v.w * v.w;
  ushort4 p;
  p.x = f2h(v.x); p.y = f2h(v.y); p.z = f2h(v.z); p.w = f2h(v.w);
  const int ks = l >> 2, lf = ((l >> 1) & 1) * 32 + n, j0 = (l & 1) * 4;
  const size_t off = (((size_t)s * 32 + tile) * 16 + ks) * 512 + (size_t)lf * 8 + j0;
  *(ushort4*)(cb16 + off) = p;
#pragma unroll
  for (int m = 1; m <= 32; m <<= 1) nrm += __shfl_xor(nrm, m);
  if (l == 0) cnorm[code] = (float)nrm;
}

// ---- main ----
// 512 blocks x 256 thr. Block owns 64 rows. Wave w: rows (w>>1)*32..+31, codes (w&1)*512..+511.
// Per wave: A (residual fp16) in 64 VGPRs, B streamed cb16->private LDS ring (8x1KB) via
// global_load_lds + manual vmcnt(6), 1 MFMA per 1KB chunk. No barriers in K-loop.
__global__ __launch_bounds__(256, 2)
void rvq_main(const float* __restrict__ cb, const float* __restrict__ xT,
              const ushort* __restrict__ cb16, const float* __restrict__ cnorm,
              float* __restrict__ out, double* __restrict__ lossbuf) {
  __shared__ __align__(16) ushort Bring[4 * 8 * 512];   // 32 KB: per-wave 8-slot ring
  __shared__ __align__(16) ushort resf16[64 * 264];     // 33 KB: fp16 residual mirror (pad 264)
  __shared__ float candv[64][6];
  __shared__ int   candi[64][6];
  __shared__ int   hist[NQ_][64];

  const int tid = threadIdx.x;
  const int w = tid >> 6, l = tid & 63, n5 = l & 31, h = l >> 5;
  const int rh = w >> 1, ch = w & 1;
  const size_t row0 = (size_t)blockIdx.x * 64;

  // stage-0 residual = x (fp16 mirror)
  {
    const int r = tid >> 2, dseg = (tid & 3) * 64;
    const float* xp = xT + (row0 + r) * D_ + dseg;
    for (int i = 0; i < 16; ++i) {
      const float4 v = *(const float4*)(xp + i * 4);
      ushort4 p; p.x = f2h(v.x); p.y = f2h(v.y); p.z = f2h(v.z); p.w = f2h(v.w);
      *(ushort4*)(resf16 + r * 264 + dseg + i * 4) = p;
    }
  }
  __syncthreads();

  for (int s = 0; s < NQ_; ++s) {
    // ===== A fragments from LDS residual (64 VGPRs, full K) =====
    half8 a[16];
#pragma unroll
    for (int ks = 0; ks < 16; ++ks) {
      const uint4 ua = *(const uint4*)(resf16 + (rh * 32 + n5) * 264 + ks * 16 + h * 8);
      a[ks] = __builtin_bit_cast(half8, ua);
    }
    float cnr[16];
#pragma unroll
    for (int t = 0; t < 16; ++t) cnr[t] = cnorm[s * K_ + ch * 512 + t * 32 + n5];

    const ushort* src = cb16 + (((size_t)s * 32 + ch * 16) * 16) * 512 + (size_t)l * 8;
    ushort* ring = Bring + w * 8 * 512;

    // preload depth 6
#pragma unroll
    for (int c = 0; c < 6; ++c) ldsdma16(src + (size_t)c * 512, ring + (c & 7) * 512);

    float v1[16], v2[16], v3[16]; uint pk[16];
#pragma unroll
    for (int r = 0; r < 16; ++r) { v1[r] = 3e38f; v2[r] = 3e38f; v3[r] = 3e38f; pk[r] = 0; }

    // ===== K-loop: 256 chunks = 16 code-tiles x 16 k-steps, barrier-free =====
    for (int t = 0; t < 16; ++t) {
      f32x16 ae, ao;
#pragma unroll
      for (int r = 0; r < 16; ++r) { ae[r] = 0.f; ao[r] = 0.f; }
#pragma unroll
      for (int ks = 0; ks < 16; ++ks) {
        const int c = t * 16 + ks;
        const int cn6 = (c + 6) & 255;              // wraps at stage tail (harmless re-loads)
        ldsdma16(src + (size_t)cn6 * 512, ring + (cn6 & 7) * 512);
        __builtin_amdgcn_s_waitcnt(0x0F70 | 6);     // vmcnt(6): chunk c resident
        const uint4 ub = *(const uint4*)(ring + (c & 7) * 512 + l * 8);
        const half8 bf = __builtin_bit_cast(half8, ub);
        if (ks & 1) ao = __builtin_amdgcn_mfma_f32_32x32x16_f16(a[ks], bf, ao, 0, 0, 0);
        else        ae = __builtin_amdgcn_mfma_f32_32x32x16_f16(a[ks], bf, ae, 0, 0, 0);
      }
      const uint c10 = (uint)(t * 32 + n5);
#pragma unroll
      for (int r = 0; r < 16; ++r) {
        const float sc = cnr[t] - 2.0f * (ae[r] + ao[r]);
        ins3(v1[r], v2[r], v3[r], pk[r], sc, c10);
      }
    }

    // cross-lane top-3 merge over the 32 code-columns (masks <=16 keep h-half)
#pragma unroll
    for (int m = 1; m <= 16; m <<= 1) {
#pragma unroll
      for (int r = 0; r < 16; ++r) {
        const float ov1 = __shfl_xor(v1[r], m), ov2 = __shfl_xor(v2[r], m), ov3 = __shfl_xor(v3[r], m);
        const uint  opk = (uint)__shfl_xor((int)pk[r], m);
        ins3(v1[r], v2[r], v3[r], pk[r], ov1, opk & 0x3FFu);
        ins3(v1[r], v2[r], v3[r], pk[r], ov2, (opk >> 10) & 0x3FFu);
        ins3(v1[r], v2[r], v3[r], pk[r], ov3, (opk >> 20) & 0x3FFu);
      }
    }
    if (n5 == 0) {
#pragma unroll
      for (int r = 0; r < 16; ++r) {
        const int rowL = rh * 32 + (r & 3) + 8 * (r >> 2) + 4 * h;  // measured C/D layout (m74/m101)
        candv[rowL][ch * 3 + 0] = v1[r]; candi[rowL][ch * 3 + 0] = ch * 512 + (int)(pk[r] & 0x3FFu);
        candv[rowL][ch * 3 + 1] = v2[r]; candi[rowL][ch * 3 + 1] = ch * 512 + (int)((pk[r] >> 10) & 0x3FFu);
        candv[rowL][ch * 3 + 2] = v3[r]; candi[rowL][ch * 3 + 2] = ch * 512 + (int)((pk[r] >> 20) & 0x3FFu);
      }
    }
    __syncthreads();

    // ===== phase 3: f64 re-eval of global fp-top-3, residual update, loss =====
    double lossW = 0.0;
    for (int it = 0; it < 16; ++it) {
      const int rowL = w * 16 + it;
      const size_t rowG = row0 + rowL;
      float w1 = 3e38f, w2 = 3e38f, w3 = 3e38f; int j1 = 0, j2 = 0, j3 = 0;
#pragma unroll
      for (int cnd = 0; cnd < 6; ++cnd) {
        const float cv = candv[rowL][cnd]; const int cidx = candi[rowL][cnd];
        if (cv < w1 || (cv == w1 && cidx < j1)) { w3 = w2; j3 = j2; w2 = w1; j2 = j1; w1 = cv; j1 = cidx; }
        else if (cv < w2 || (cv == w2 && cidx < j2)) { w3 = w2; j3 = j2; w2 = cv; j2 = cidx; }
        else if (cv < w3 || (cv == w3 && cidx < j3)) { w3 = cv; j3 = cidx; }
      }
      const float4 xv4 = *(const float4*)(xT + rowG * D_ + l * 4);
      double r64[4] = {(double)xv4.x, (double)xv4.y, (double)xv4.z, (double)xv4.w};
      for (int q = 0; q < s; ++q) {
        const float4 cq = *(const float4*)(cb + ((size_t)q * K_ + hist[q][rowL]) * D_ + l * 4);
        r64[0] -= (double)cq.x; r64[1] -= (double)cq.y; r64[2] -= (double)cq.z; r64[3] -= (double)cq.w;
      }
      const int cs[3] = {j1, j2, j3};
      double dd[3]; float4 crow[3];
#pragma unroll
      for (int k = 0; k < 3; ++k) {
        crow[k] = *(const float4*)(cb + ((size_t)s * K_ + cs[k]) * D_ + l * 4);
        const double u0 = r64[0] - (double)crow[k].x, u1 = r64[1] - (double)crow[k].y;
        const double u2 = r64[2] - (double)crow[k].z, u3 = r64[3] - (double)crow[k].w;
        dd[k] = u0 * u0 + u1 * u1 + u2 * u2 + u3 * u3;
      }
#pragma unroll
      for (int m = 1; m <= 32; m <<= 1) {
        dd[0] += __shfl_xor(dd[0], m); dd[1] += __shfl_xor(dd[1], m); dd[2] += __shfl_xor(dd[2], m);
      }
      int win = cs[0]; double dw = dd[0]; float4 cw = crow[0];
      if (dd[1] < dw || (dd[1] == dw && cs[1] < win)) { win = cs[1]; dw = dd[1]; cw = crow[1]; }
      if (dd[2] < dw || (dd[2] == dw && cs[2] < win)) { win = cs[2]; dw = dd[2]; cw = crow[2]; }
      const double nr0 = r64[0] - (double)cw.x, nr1 = r64[1] - (double)cw.y;
      const double nr2 = r64[2] - (double)cw.z, nr3 = r64[3] - (double)cw.w;
      if (s < NQ_ - 1) {
        ushort4 p;
        p.x = f2h((float)nr0); p.y = f2h((float)nr1); p.z = f2h((float)nr2); p.w = f2h((float)nr3);
        *(ushort4*)(resf16 + rowL * 264 + l * 4) = p;
      } else {
        float4 o;
        o.x = (float)((double)xv4.x - nr0); o.y = (float)((double)xv4.y - nr1);
        o.z = (float)((double)xv4.z - nr2); o.w = (float)((double)xv4.w - nr3);
        *(float4*)(out + rowG * D_ + l * 4) = o;
      }
      if (l == 0) {
        hist[s][rowL] = win;
        out[IDX_OFF + (size_t)s * (B_ * T_) + rowG] = (float)win;
        lossW += dw;
      }
    }
    if (l == 0) atomicAdd(&lossbuf[s], lossW);
    __syncthreads();
  }
}

__global__ void rvq_loss(const double* __restrict__ lossbuf, float* __restrict__ out) {
  const int s = threadIdx.x;
  if (s < NQ_) out[LOSS_OFF + s] = (float)(2.0 * lossbuf[s] / (double)((size_t)B_ * T_ * D_));
}

extern "C" void kernel_launch(void* const* d_in, const int* in_sizes, int n_in,
                              void* d_out, int out_size, void* d_ws, size_t ws_size,
                              hipStream_t stream) {
  const float* x  = (const float*)d_in[0];   // [B, D, T] f32
  const float* cb = (const float*)d_in[1];   // [NQ, K, D] f32
  float* out = (float*)d_out;
  char* ws = (char*)d_ws;
  float*  xTp   = (float*)(ws + XT_OFF);
  ushort* cb16p = (ushort*)(ws + CB16_OFF);
  float*  cnp   = (float*)(ws + CN_OFF);
  double* lbp   = (double*)(ws + LB_OFF);

  hipMemsetAsync(ws + LB_OFF, 0, NQ_ * sizeof(double), stream);
  prep_xT<<<2048, 256, 0, stream>>>(x, xTp);
  prep_cb16<<<2048, 256, 0, stream>>>(cb, cb16p, cnp);
  rvq_main<<<512, 256, 0, stream>>>(cb, xTp, cb16p, cnp, out, lbp);
  rvq_loss<<<1, 64, 0, stream>>>(lbp, out);
}

// Round 4
// 740.839 us; speedup vs baseline: 3.1139x; 3.1139x over previous
//
#include <hip/hip_runtime.h>

#define B_   8
#define D_   256
#define T_   4096
#define NQ_  8
#define K_   1024

#define IDX_OFF  ((size_t)B_ * T_ * D_)             // 8388608
#define LOSS_OFF (IDX_OFF + (size_t)NQ_ * B_ * T_)  // 8650752

// ---- workspace layout (bytes) ----
#define XT_OFF   0ull                      // float xT[32768][256] (32 MB)
#define CB16_OFF 33554432ull               // fp16 codebook in MFMA A-frag order (4 MB)
#define CN_OFF   37748736ull               // float cnorm[8192]
#define LB_OFF   37781504ull               // double lossbuf[8]

#define RST 260                            // res row stride (floats); swizzle handles banks

typedef _Float16 half8 __attribute__((ext_vector_type(8)));   // 4 VGPR MFMA frag
typedef float   f32x16 __attribute__((ext_vector_type(16)));  // MFMA C/D

__device__ __forceinline__ ushort f2h(float f) {
  return __builtin_bit_cast(ushort, (_Float16)f);
}
__device__ __forceinline__ int swz(int blk) { return blk ^ ((blk >> 2) & 3); } // 8-dim block swizzle

// running sorted top-3 MIN (v1<=v2<=v3), pk: [9:0]=i1 [19:10]=i2 [29:20]=i3
__device__ __forceinline__ void ins3min(float& v1, float& v2, float& v3, uint& pk, float sc, uint c10) {
  if (sc < v1)      { v3 = v2; v2 = v1; v1 = sc; pk = ((pk & 0xFFFFFu) << 10) | c10; }
  else if (sc < v2) { v3 = v2; v2 = sc; pk = (pk & 0x3FFu) | (c10 << 10) | (((pk >> 10) & 0x3FFu) << 20); }
  else if (sc < v3) { v3 = sc; pk = (pk & 0xFFFFFu) | (c10 << 20); }
}

// ---- prep 1: x [B,D,T] -> xT f32 [row=b*T+t][d] ----
__global__ void prep_xT(const float* __restrict__ x, float* __restrict__ xT) {
  __shared__ float tile[64][65];
  const int bidx = blockIdx.x;                 // 8 b * 4 dchunk * 64 tchunk
  const int b = bidx >> 8, dc = (bidx >> 6) & 3, tc = bidx & 63;
  const int d0 = dc * 64, t0 = tc * 64;
  const int tid = threadIdx.x;
  {
    const int tt = tid & 63, dg = tid >> 6;
    for (int i = 0; i < 16; ++i) {
      const int d = dg * 16 + i;
      tile[d][tt] = x[((size_t)(b * D_ + d0 + d)) * T_ + t0 + tt];
    }
  }
  __syncthreads();
  {
    const int dw = tid & 63, tg = tid >> 6;
    for (int i = 0; i < 16; ++i) {
      const int t = tg * 16 + i;
      xT[((size_t)b * T_ + t0 + t) * D_ + d0 + dw] = tile[dw][t];
    }
  }
}

// ---- prep 2: cb f32 -> fp16 MFMA A-frag order + f64-accurate cnorm (f32 out) ----
// layout: cb16[stage][tile(code>>5)][ks(k>>4)][lane][8]; lane = ((k>>3)&1)*32 + (code&31), j=k&7
__global__ void prep_cb16(const float* __restrict__ cb, ushort* __restrict__ cb16,
                          float* __restrict__ cnorm) {
  const int tid = threadIdx.x, w = tid >> 6, l = tid & 63;
  const int code = blockIdx.x * 4 + w;         // grid 2048
  const int s = code >> 10, ci = code & 1023, tile = ci >> 5, n = ci & 31;
  const float* row = cb + (size_t)code * D_;
  const float4 v = *(const float4*)(row + l * 4);
  double nrm = (double)v.x * v.x + (double)v.y * v.y + (double)v.z * v.z + (double)v.w * v.w;
  ushort4 p;
  p.x = f2h(v.x); p.y = f2h(v.y); p.z = f2h(v.z); p.w = f2h(v.w);
  const int ks = l >> 2, lf = ((l >> 1) & 1) * 32 + n, j0 = (l & 1) * 4;
  const size_t off = (((size_t)s * 32 + tile) * 16 + ks) * 512 + (size_t)lf * 8 + j0;
  *(ushort4*)(cb16 + off) = p;
#pragma unroll
  for (int m = 1; m <= 32; m <<= 1) nrm += __shfl_xor(nrm, m);
  if (l == 0) cnorm[code] = (float)nrm;
}

// ---- main: 1024 blocks x 256 thr; block = 32 rows; wave w = codes w*256..+255 (8 tiles) ----
// K-loop: A(codes) global->VGPR (L2-resident), B(residual fp16) in 64 regs, top-3 in 4 regs.
__attribute__((amdgpu_waves_per_eu(2, 2)))
__global__ __launch_bounds__(256)
void rvq_main(const float* __restrict__ cb, const float* __restrict__ xT,
              const ushort* __restrict__ cb16, const float* __restrict__ cnorm,
              float* __restrict__ out, double* __restrict__ lossbuf) {
  __shared__ __align__(16) float resHi[32 * RST];   // 33.3 KB
  __shared__ __align__(16) float resLo[32 * RST];   // 33.3 KB (double-single pair)
  __shared__ float candm[32][12];
  __shared__ int   candc[32][12];

  const int tid = threadIdx.x;
  const int w = tid >> 6, l = tid & 63, n5 = l & 31, h = l >> 5;
  const size_t row0 = (size_t)blockIdx.x * 32;

  // ---- init: residual pair = (x, 0) ----
  {
    const int r = tid >> 3, dq = tid & 7;
#pragma unroll
    for (int cc = 0; cc < 4; ++cc) {
      const int blk = dq * 4 + cc;
      const float* xp = xT + (row0 + r) * D_ + blk * 8;
      const float4 x0 = *(const float4*)xp, x1 = *(const float4*)(xp + 4);
      const int po = r * RST + swz(blk) * 8;
      *(float4*)(resHi + po) = x0; *(float4*)(resHi + po + 4) = x1;
      *(float4*)(resLo + po) = make_float4(0, 0, 0, 0);
      *(float4*)(resLo + po + 4) = make_float4(0, 0, 0, 0);
    }
  }
  __syncthreads();

  for (int s = 0; s < NQ_; ++s) {
    // ===== B fragments: residual fp16, n = n5, k = ks*16 + h*8 + j =====
    half8 b[16];
#pragma unroll
    for (int ks = 0; ks < 16; ++ks) {
      const int po = n5 * RST + swz(ks * 2 + h) * 8;
      const float4 f0 = *(const float4*)(resHi + po);
      const float4 f1 = *(const float4*)(resHi + po + 4);
      half8 bb;
      bb[0] = (_Float16)f0.x; bb[1] = (_Float16)f0.y; bb[2] = (_Float16)f0.z; bb[3] = (_Float16)f0.w;
      bb[4] = (_Float16)f1.x; bb[5] = (_Float16)f1.y; bb[6] = (_Float16)f1.z; bb[7] = (_Float16)f1.w;
      b[ks] = bb;
    }

    // ===== K-loop: 8 tiles x 16 MFMAs; per-lane top-3 over own x-row =====
    float v1 = 3e38f, v2 = 3e38f, v3 = 3e38f; uint pk = 0;
    for (int tt = 0; tt < 8; ++tt) {
      const int t = w * 8 + tt;
      const uint4* ap = (const uint4*)(cb16 + ((size_t)(s * 32 + t) * 16) * 512) + l;
      f32x16 acc;
#pragma unroll
      for (int r = 0; r < 16; ++r) acc[r] = 0.0f;
#pragma unroll
      for (int ks = 0; ks < 16; ++ks) {
        const uint4 av = ap[(size_t)ks * 64];
        acc = __builtin_amdgcn_mfma_f32_32x32x16_f16(__builtin_bit_cast(half8, av), b[ks], acc, 0, 0, 0);
      }
      const float* cnb = cnorm + s * K_ + t * 32 + h * 4;
      const float4 cq0 = *(const float4*)(cnb);
      const float4 cq1 = *(const float4*)(cnb + 8);
      const float4 cq2 = *(const float4*)(cnb + 16);
      const float4 cq3 = *(const float4*)(cnb + 24);
      const float cna[16] = {cq0.x, cq0.y, cq0.z, cq0.w, cq1.x, cq1.y, cq1.z, cq1.w,
                             cq2.x, cq2.y, cq2.z, cq2.w, cq3.x, cq3.y, cq3.z, cq3.w};
#pragma unroll
      for (int r = 0; r < 16; ++r) {
        const float sc = cna[r] - 2.0f * acc[r];
        const uint code = (uint)(t * 32 + (r & 3) + 8 * (r >> 2) + 4 * h);
        ins3min(v1, v2, v3, pk, sc, code);
      }
    }
    // merge h-halves (lane l <-> l^32, same x-row, disjoint codes)
    {
      const float ov1 = __shfl_xor(v1, 32), ov2 = __shfl_xor(v2, 32), ov3 = __shfl_xor(v3, 32);
      const uint opk = (uint)__shfl_xor((int)pk, 32);
      ins3min(v1, v2, v3, pk, ov1, opk & 0x3FFu);
      ins3min(v1, v2, v3, pk, ov2, (opk >> 10) & 0x3FFu);
      ins3min(v1, v2, v3, pk, ov3, (opk >> 20) & 0x3FFu);
    }
    if (h == 0) {
      candm[n5][w * 3 + 0] = v1; candc[n5][w * 3 + 0] = (int)(pk & 0x3FFu);
      candm[n5][w * 3 + 1] = v2; candc[n5][w * 3 + 1] = (int)((pk >> 10) & 0x3FFu);
      candm[n5][w * 3 + 2] = v3; candc[n5][w * 3 + 2] = (int)((pk >> 20) & 0x3FFu);
    }
    __syncthreads();

    // ===== phase 3: wave w rows w*8..+7; 8 lanes/row x 32 dims; f64 re-eval of top-3-of-12 =====
    double lossW = 0.0;
    {
      const int rowL = w * 8 + (l >> 3);
      const int dq = l & 7;
      float m1 = 3e38f, m2 = 3e38f, m3 = 3e38f; int c1 = 0, c2 = 0, c3 = 0;
#pragma unroll
      for (int cd = 0; cd < 12; ++cd) {
        const float mv = candm[rowL][cd]; const int cx = candc[rowL][cd];
        if (mv < m1 || (mv == m1 && cx < c1)) { m3 = m2; c3 = c2; m2 = m1; c2 = c1; m1 = mv; c1 = cx; }
        else if (mv < m2 || (mv == m2 && cx < c2)) { m3 = m2; c3 = c2; m2 = mv; c2 = cx; }
        else if (mv < m3 || (mv == m3 && cx < c3)) { m3 = mv; c3 = cx; }
      }
      const float* cbs = cb + (size_t)s * K_ * D_;
      const float* cr0 = cbs + (size_t)c1 * D_;
      const float* cr1 = cbs + (size_t)c2 * D_;
      const float* cr2 = cbs + (size_t)c3 * D_;
      double dd0 = 0.0, dd1 = 0.0, dd2 = 0.0;
#pragma unroll
      for (int cc = 0; cc < 4; ++cc) {
        const int blk = dq * 4 + cc;
        const int po = rowL * RST + swz(blk) * 8;
        const float4 h0 = *(const float4*)(resHi + po), h1 = *(const float4*)(resHi + po + 4);
        const float4 e0 = *(const float4*)(resLo + po), e1 = *(const float4*)(resLo + po + 4);
        const double r64[8] = {(double)h0.x + e0.x, (double)h0.y + e0.y, (double)h0.z + e0.z,
                               (double)h0.w + e0.w, (double)h1.x + e1.x, (double)h1.y + e1.y,
                               (double)h1.z + e1.z, (double)h1.w + e1.w};
        const int go = blk * 8;
        const float4 a0 = *(const float4*)(cr0 + go), a1 = *(const float4*)(cr0 + go + 4);
        const float4 b0 = *(const float4*)(cr1 + go), b1 = *(const float4*)(cr1 + go + 4);
        const float4 g0 = *(const float4*)(cr2 + go), g1 = *(const float4*)(cr2 + go + 4);
        const float af[8] = {a0.x, a0.y, a0.z, a0.w, a1.x, a1.y, a1.z, a1.w};
        const float bf[8] = {b0.x, b0.y, b0.z, b0.w, b1.x, b1.y, b1.z, b1.w};
        const float gf[8] = {g0.x, g0.y, g0.z, g0.w, g1.x, g1.y, g1.z, g1.w};
#pragma unroll
        for (int j = 0; j < 8; ++j) {
          const double u = r64[j] - (double)af[j]; dd0 += u * u;
          const double v = r64[j] - (double)bf[j]; dd1 += v * v;
          const double g = r64[j] - (double)gf[j]; dd2 += g * g;
        }
      }
#pragma unroll
      for (int m = 1; m <= 4; m <<= 1) {
        dd0 += __shfl_xor(dd0, m); dd1 += __shfl_xor(dd1, m); dd2 += __shfl_xor(dd2, m);
      }
      int win = c1; double dwn = dd0;
      if (dd1 < dwn || (dd1 == dwn && c2 < win)) { win = c2; dwn = dd1; }
      if (dd2 < dwn || (dd2 == dwn && c3 < win)) { win = c3; dwn = dd2; }
      const float* crw = cbs + (size_t)win * D_;
#pragma unroll
      for (int cc = 0; cc < 4; ++cc) {
        const int blk = dq * 4 + cc;
        const int po = rowL * RST + swz(blk) * 8;
        const float4 h0 = *(const float4*)(resHi + po), h1 = *(const float4*)(resHi + po + 4);
        const float4 e0 = *(const float4*)(resLo + po), e1 = *(const float4*)(resLo + po + 4);
        const int go = blk * 8;
        const float4 w0 = *(const float4*)(crw + go), w1 = *(const float4*)(crw + go + 4);
        const double n64[8] = {((double)h0.x + e0.x) - w0.x, ((double)h0.y + e0.y) - w0.y,
                               ((double)h0.z + e0.z) - w0.z, ((double)h0.w + e0.w) - w0.w,
                               ((double)h1.x + e1.x) - w1.x, ((double)h1.y + e1.y) - w1.y,
                               ((double)h1.z + e1.z) - w1.z, ((double)h1.w + e1.w) - w1.w};
        if (s < NQ_ - 1) {
          float hi[8], lo[8];
#pragma unroll
          for (int j = 0; j < 8; ++j) { hi[j] = (float)n64[j]; lo[j] = (float)(n64[j] - (double)hi[j]); }
          *(float4*)(resHi + po)     = make_float4(hi[0], hi[1], hi[2], hi[3]);
          *(float4*)(resHi + po + 4) = make_float4(hi[4], hi[5], hi[6], hi[7]);
          *(float4*)(resLo + po)     = make_float4(lo[0], lo[1], lo[2], lo[3]);
          *(float4*)(resLo + po + 4) = make_float4(lo[4], lo[5], lo[6], lo[7]);
        } else {
          const float* xp = xT + (row0 + rowL) * D_ + go;
          const float4 x0 = *(const float4*)xp, x1 = *(const float4*)(xp + 4);
          float o[8];
          o[0] = (float)((double)x0.x - n64[0]); o[1] = (float)((double)x0.y - n64[1]);
          o[2] = (float)((double)x0.z - n64[2]); o[3] = (float)((double)x0.w - n64[3]);
          o[4] = (float)((double)x1.x - n64[4]); o[5] = (float)((double)x1.y - n64[5]);
          o[6] = (float)((double)x1.z - n64[6]); o[7] = (float)((double)x1.w - n64[7]);
          float* od = out + (row0 + rowL) * D_ + go;
          *(float4*)od       = make_float4(o[0], o[1], o[2], o[3]);
          *(float4*)(od + 4) = make_float4(o[4], o[5], o[6], o[7]);
        }
      }
      if (dq == 0) {
        out[IDX_OFF + (size_t)s * (B_ * T_) + row0 + rowL] = (float)win;
        lossW = dwn;
      }
    }
#pragma unroll
    for (int m = 1; m <= 32; m <<= 1) lossW += __shfl_xor(lossW, m);
    if (l == 0) atomicAdd(&lossbuf[s], lossW);
    __syncthreads();
  }
}

__global__ void rvq_loss(const double* __restrict__ lossbuf, float* __restrict__ out) {
  const int s = threadIdx.x;
  if (s < NQ_) out[LOSS_OFF + s] = (float)(2.0 * lossbuf[s] / (double)((size_t)B_ * T_ * D_));
}

extern "C" void kernel_launch(void* const* d_in, const int* in_sizes, int n_in,
                              void* d_out, int out_size, void* d_ws, size_t ws_size,
                              hipStream_t stream) {
  const float* x  = (const float*)d_in[0];   // [B, D, T] f32
  const float* cb = (const float*)d_in[1];   // [NQ, K, D] f32
  float* out = (float*)d_out;
  char* ws = (char*)d_ws;
  float*  xTp   = (float*)(ws + XT_OFF);
  ushort* cb16p = (ushort*)(ws + CB16_OFF);
  float*  cnp   = (float*)(ws + CN_OFF);
  double* lbp   = (double*)(ws + LB_OFF);

  hipMemsetAsync(ws + LB_OFF, 0, NQ_ * sizeof(double), stream);
  prep_xT<<<2048, 256, 0, stream>>>(x, xTp);
  prep_cb16<<<2048, 256, 0, stream>>>(cb, cb16p, cnp);
  rvq_main<<<1024, 256, 0, stream>>>(cb, xTp, cb16p, cnp, out, lbp);
  rvq_loss<<<1, 64, 0, stream>>>(lbp, out);
}